// Round 1
// baseline (151.975 us; speedup 1.0000x reference)
//
#include <hip/hip_runtime.h>
#include <stdint.h>

// Problem constants
#define B_    16
#define CIN_  128
#define COUT_ 128
#define H_    64
#define W_    64
#define L_    4096            // H*W
#define KK_   1152            // CIN * 9, GEMM K dim, ordering kk = k*128 + c (k = k1*3+k2)

typedef unsigned short u16;
typedef __bf16 bf16x8 __attribute__((ext_vector_type(8)));
typedef float  floatx4 __attribute__((ext_vector_type(4)));

__device__ __forceinline__ u16 f2bf(float f) {
    uint32_t u = __builtin_bit_cast(uint32_t, f);
    uint32_t r = u + 0x7FFFu + ((u >> 16) & 1u);   // round-to-nearest-even
    return (u16)(r >> 16);
}

// ---------------------------------------------------------------------------
// P1: x [B][CIN][L] f32  ->  xT [B][L][CIN] bf16
// block = 256 threads, tile = 128c x 64l for one batch. LDS transpose.
// ---------------------------------------------------------------------------
__global__ void lmc_transpose_kernel(const float* __restrict__ x, u16* __restrict__ xT) {
    __shared__ u16 tile[64][CIN_ + 8];   // [l_local][c], +8 halves pad (16B)
    const int b   = blockIdx.y;
    const int l0  = blockIdx.x * 64;
    const int tid = threadIdx.x;

    // phase A: read coalesced in l, scatter bf16 into tile[l][c]
    {
        const int c  = tid >> 1;            // 0..127
        const int j0 = (tid & 1) * 32;      // l sub-offset
        const float* src = x + ((size_t)b * CIN_ + c) * L_ + l0 + j0;
        #pragma unroll
        for (int j = 0; j < 32; j += 4) {
            float4 v = *reinterpret_cast<const float4*>(src + j);
            tile[j0 + j + 0][c] = f2bf(v.x);
            tile[j0 + j + 1][c] = f2bf(v.y);
            tile[j0 + j + 2][c] = f2bf(v.z);
            tile[j0 + j + 3][c] = f2bf(v.w);
        }
    }
    __syncthreads();
    // phase B: write coalesced in c
    {
        const int l    = tid >> 2;          // 0..63
        const int cseg = (tid & 3) * 32;    // 0,32,64,96
        u16* dst = xT + ((size_t)b * L_ + l0 + l) * CIN_ + cseg;
        #pragma unroll
        for (int i = 0; i < 32; i += 8) {
            *reinterpret_cast<uint4*>(dst + i) =
                *reinterpret_cast<const uint4*>(&tile[l][cseg + i]);
        }
    }
}

// ---------------------------------------------------------------------------
// P2a: weight [COUT][CIN][3][3] f32 -> wb [COUT][ kk = k*128 + c ] bf16
// ---------------------------------------------------------------------------
__global__ void lmc_wreorder_kernel(const float* __restrict__ w, u16* __restrict__ wb) {
    const int idx = blockIdx.x * 256 + threadIdx.x;   // 0..147455, exact
    const int o   = idx / KK_;
    const int rem = idx - o * KK_;
    const int k   = rem >> 7;      // 0..8
    const int c   = rem & 127;
    wb[idx] = f2bf(w[(size_t)o * KK_ + c * 9 + k]);
}

// ---------------------------------------------------------------------------
// P2b: mb[o][l] = bias[o] + sum_k mw[o][k] * mask[k][l]   (fp32, b-independent)
// ---------------------------------------------------------------------------
__global__ void lmc_mb_kernel(const float* __restrict__ mask, const float* __restrict__ mw,
                              const float* __restrict__ bias, float* __restrict__ mb) {
    const int idx = blockIdx.x * 256 + threadIdx.x;   // o*4096 + l, exact
    const int o = idx >> 12;
    const int l = idx & 4095;
    float s = bias[o];
    #pragma unroll
    for (int k = 0; k < 9; ++k) s += mw[o * 9 + k] * mask[k * L_ + l];
    mb[idx] = s;
}

// ---------------------------------------------------------------------------
// Main implicit GEMM: out[b][o][l] = sum_kk wb[o][kk] * P[kk][l]  + mb[o][l]
// P[k*128+c][l] = mask[k][l] ? xT[b][shift_k(l)][c] : 0
// tile 128(o) x 128(l), BK=64 (one tap k, 64 channels), 4 waves of 64x64,
// mfma_f32_16x16x32_bf16. LDS rows padded to 72 halves.
// ---------------------------------------------------------------------------
#define LDSS 72

__global__ __launch_bounds__(256, 2)
void lmc_gemm_kernel(const u16* __restrict__ xT, const u16* __restrict__ wb,
                     const float* __restrict__ mask, const float* __restrict__ mb,
                     float* __restrict__ out) {
    __shared__ u16 A_lds[128 * LDSS];   // [o_local][kk_local]
    __shared__ u16 B_lds[128 * LDSS];   // [l_local][kk_local]

    const int b    = blockIdx.y;
    const int l0   = blockIdx.x * 128;
    const int tid  = threadIdx.x;
    const int lane = tid & 63;
    const int wv   = tid >> 6;
    const int wm   = (wv >> 1) * 64;   // wave row (o) offset
    const int wn   = (wv & 1) * 64;    // wave col (l) offset

    const int lrow = lane & 15;
    const int quad = lane >> 4;

    floatx4 acc[4][4];
    #pragma unroll
    for (int i = 0; i < 4; ++i)
        #pragma unroll
        for (int j = 0; j < 4; ++j)
            acc[i][j] = (floatx4){0.f, 0.f, 0.f, 0.f};

    const int srow = tid >> 3;   // 0..31
    const int ssub = tid & 7;    // 0..7 -> 16B segment within 64-kk row chunk

    for (int t = 0; t < 18; ++t) {
        const int k  = t >> 1;
        const int c0 = (t & 1) * 64;
        const int dy = k / 3 - 1;
        const int dx = k - (k / 3) * 3 - 1;

        // ---- stage A (weight): rows = o, contiguous kk
        {
            const u16* asrc = wb + t * 64 + ssub * 8;
            #pragma unroll
            for (int p = 0; p < 4; ++p) {
                const int row = p * 32 + srow;
                uint4 v = *reinterpret_cast<const uint4*>(asrc + (size_t)row * KK_);
                *reinterpret_cast<uint4*>(&A_lds[row * LDSS + ssub * 8]) = v;
            }
        }
        // ---- stage B (masked shifted x): rows = l, contiguous c
        {
            #pragma unroll
            for (int p = 0; p < 4; ++p) {
                const int row = p * 32 + srow;
                const int l   = l0 + row;
                const int y   = l >> 6, xx = l & 63;
                const int sy  = y + dy, sx = xx + dx;
                const bool valid = ((unsigned)sy < 64u) && ((unsigned)sx < 64u);
                int lsrc = sy * 64 + sx;
                lsrc = min(max(lsrc, 0), L_ - 1);
                const float mv = mask[k * L_ + l];
                const uint32_t keep = (valid && (mv != 0.0f)) ? 0xFFFFFFFFu : 0u;
                const u16* bsrc = xT + ((size_t)b * L_ + lsrc) * CIN_ + c0 + ssub * 8;
                uint4 v = *reinterpret_cast<const uint4*>(bsrc);
                v.x &= keep; v.y &= keep; v.z &= keep; v.w &= keep;
                *reinterpret_cast<uint4*>(&B_lds[row * LDSS + ssub * 8]) = v;
            }
        }
        __syncthreads();

        // ---- compute: 2 ksteps x 16 MFMA
        #pragma unroll
        for (int ks = 0; ks < 2; ++ks) {
            const int ko = ks * 32 + quad * 8;
            bf16x8 af[4], bfr[4];
            #pragma unroll
            for (int i = 0; i < 4; ++i)
                af[i] = *reinterpret_cast<const bf16x8*>(&A_lds[(wm + i * 16 + lrow) * LDSS + ko]);
            #pragma unroll
            for (int j = 0; j < 4; ++j)
                bfr[j] = *reinterpret_cast<const bf16x8*>(&B_lds[(wn + j * 16 + lrow) * LDSS + ko]);
            #pragma unroll
            for (int i = 0; i < 4; ++i)
                #pragma unroll
                for (int j = 0; j < 4; ++j)
                    acc[i][j] = __builtin_amdgcn_mfma_f32_16x16x32_bf16(af[i], bfr[j], acc[i][j], 0, 0, 0);
        }
        __syncthreads();
    }

    // ---- epilogue: C/D layout col = lane&15, row = quad*4 + r
    #pragma unroll
    for (int i = 0; i < 4; ++i) {
        #pragma unroll
        for (int j = 0; j < 4; ++j) {
            const int l = l0 + wn + j * 16 + lrow;
            #pragma unroll
            for (int r = 0; r < 4; ++r) {
                const int o = wm + i * 16 + quad * 4 + r;
                out[((size_t)b * COUT_ + o) * L_ + l] = acc[i][j][r] + mb[o * L_ + l];
            }
        }
    }
}

// ---------------------------------------------------------------------------
extern "C" void kernel_launch(void* const* d_in, const int* in_sizes, int n_in,
                              void* d_out, int out_size, void* d_ws, size_t ws_size,
                              hipStream_t stream) {
    const float* x      = (const float*)d_in[0];
    const float* mask   = (const float*)d_in[1];
    const float* weight = (const float*)d_in[2];
    const float* mw     = (const float*)d_in[3];
    const float* bias   = (const float*)d_in[4];
    float* out = (float*)d_out;

    char* ws = (char*)d_ws;
    u16*   xT = (u16*)ws;                                   // 16 MB  [B][L][CIN] bf16
    u16*   wb = (u16*)(ws + 16777216);                      // 288 KB [COUT][1152] bf16
    float* mb = (float*)(ws + 16777216 + 294912);           // 2 MB   [COUT][L] f32

    lmc_transpose_kernel<<<dim3(L_ / 64, B_), 256, 0, stream>>>(x, xT);
    lmc_wreorder_kernel<<<(COUT_ * KK_) / 256, 256, 0, stream>>>(weight, wb);
    lmc_mb_kernel<<<(COUT_ * L_) / 256, 256, 0, stream>>>(mask, mw, bias, mb);
    lmc_gemm_kernel<<<dim3(L_ / 128, B_), 256, 0, stream>>>(xT, wb, mask, mb, out);
}

// Round 3
// 126.863 us; speedup vs baseline: 1.1979x; 1.1979x over previous
//
#include <hip/hip_runtime.h>
#include <stdint.h>

#define B_    16
#define CIN_  128
#define COUT_ 128
#define H_    64
#define W_    64
#define L_    4096
#define KK_   1152
#define PW_   66                 // padded image dim (halo 1 each side)
#define PPIX_ (PW_ * PW_)        // 4356

typedef unsigned short u16;
typedef __bf16 bf16x8 __attribute__((ext_vector_type(8)));
typedef float  floatx4 __attribute__((ext_vector_type(4)));
typedef uint32_t u32x4 __attribute__((ext_vector_type(4)));

typedef const __attribute__((address_space(1))) uint32_t* gptr_t;
typedef __attribute__((address_space(3))) uint32_t*       lptr_t;

__device__ __forceinline__ void async_copy16(const void* g, void* l) {
    // stages 64 lanes x 16 B = 1024 B; LDS dest = wave-uniform base + lane*16
    __builtin_amdgcn_global_load_lds((gptr_t)g, (lptr_t)l, 16, 0, 0);
}

__device__ __forceinline__ u16 f2bf(float f) {
    uint32_t u = __builtin_bit_cast(uint32_t, f);
    uint32_t r = u + 0x7FFFu + ((u >> 16) & 1u);   // round-to-nearest-even
    return (u16)(r >> 16);
}

// ---------------------------------------------------------------------------
// P1: x [B][CIN][64][64] f32 -> xTp [B][66][66][CIN] bf16, halo zeroed.
// ---------------------------------------------------------------------------
__global__ void lmc_transpose_kernel(const float* __restrict__ x, u16* __restrict__ xTp) {
    __shared__ u16 tile[64][CIN_ + 8];
    const int b   = blockIdx.y;
    const int y   = blockIdx.x;        // 0..63
    const int tid = threadIdx.x;

    // phase A: read coalesced along l, convert, scatter into tile[x][c]
    {
        const int c  = tid >> 1;
        const int x0 = (tid & 1) * 32;
        const float* src = x + ((size_t)b * CIN_ + c) * L_ + y * 64 + x0;
        #pragma unroll
        for (int j = 0; j < 32; j += 4) {
            float4 v = *reinterpret_cast<const float4*>(src + j);
            tile[x0 + j + 0][c] = f2bf(v.x);
            tile[x0 + j + 1][c] = f2bf(v.y);
            tile[x0 + j + 2][c] = f2bf(v.z);
            tile[x0 + j + 3][c] = f2bf(v.w);
        }
    }
    __syncthreads();

    u16* dstrow = xTp + ((size_t)(b * PW_ + (y + 1)) * PW_) * CIN_;  // pixel (y+1, 0)
    // phase B: write interior pixels (y+1, x+1), coalesced in c
    {
        const int xx   = tid >> 2;
        const int cseg = (tid & 3) * 32;
        u16* dst = dstrow + (size_t)(xx + 1) * CIN_ + cseg;
        #pragma unroll
        for (int i = 0; i < 32; i += 8) {
            *reinterpret_cast<uint4*>(dst + i) =
                *reinterpret_cast<const uint4*>(&tile[xx][cseg + i]);
        }
    }
    const uint4 z = {0u, 0u, 0u, 0u};
    // x-halo: pixels (y+1, 0) and (y+1, 65)
    if (tid < 32) {
        const int pix = (tid >> 4) ? 65 : 0;
        *reinterpret_cast<uint4*>(dstrow + (size_t)pix * CIN_ + (tid & 15) * 8) = z;
    }
    // y-halo rows 0 and 65
    if (y == 0 || y == 63) {
        u16* brow = xTp + ((size_t)(b * PW_ + (y == 0 ? 0 : 65)) * PW_) * CIN_;
        for (int i = tid; i < (PW_ * CIN_) / 8; i += 256)   // 1056 uint4
            reinterpret_cast<uint4*>(brow)[i] = z;
    }
}

// ---------------------------------------------------------------------------
// P2 fused: blocks 0..127  -> mb[o][l] = bias[o] + sum_k mw[o][k]*mask[k][l]
//           blocks 128..191 -> wb2[k][o][c] = bf16(weight[o][c][k])
// ---------------------------------------------------------------------------
__global__ void lmc_prep_kernel(const float* __restrict__ mask, const float* __restrict__ mw,
                                const float* __restrict__ bias, const float* __restrict__ w,
                                float* __restrict__ mb, u16* __restrict__ wb2) {
    const int bid = blockIdx.x, tid = threadIdx.x;
    if (bid < 128) {
        const int o = bid;
        float m[9];
        #pragma unroll
        for (int k = 0; k < 9; ++k) m[k] = mw[o * 9 + k];
        const float bs = bias[o];
        for (int l = tid; l < L_; l += 256) {
            float s = bs;
            #pragma unroll
            for (int k = 0; k < 9; ++k) s += m[k] * mask[k * L_ + l];
            mb[o * L_ + l] = s;
        }
    } else {
        const int base = (bid - 128) * 2304;
        #pragma unroll
        for (int i = 0; i < 9; ++i) {
            const int e = base + i * 256 + tid;        // 0..147455 exact
            const int k = e >> 14;                     // /16384
            const int rem = e & 16383;
            const int o = rem >> 7, c = rem & 127;
            wb2[e] = f2bf(w[(size_t)o * KK_ + c * 9 + k]);
        }
    }
}

// ---------------------------------------------------------------------------
// Main GEMM: out[b][o][l] = sum_k mask[k,l] * (sum_c wb2[k][o][c]*xTp[b][pix_k(l)][c]) + mb[o][l]
// 128(o) x 128(l) tile, BK=128 (one tap), 4 waves of 64x64, mfma 16x16x32 bf16.
// Staging via global_load_lds(16B), LDS rows 256 B unpadded with XOR-8 chunk swizzle.
// Mask applied as bitwise AND on B-fragments (mask is binary -> exact).
// ---------------------------------------------------------------------------
__global__ __launch_bounds__(256, 2)
void lmc_gemm_kernel(const u16* __restrict__ xTp, const u16* __restrict__ wb2,
                     const float* __restrict__ mask, const float* __restrict__ mb,
                     float* __restrict__ out) {
    __shared__ u16 A_lds[128 * 128];   // [o][c]  row stride 256 B
    __shared__ u16 B_lds[128 * 128];   // [l][c]

    const int b    = blockIdx.y;
    const int l0   = blockIdx.x * 128;
    const int tid  = threadIdx.x;
    const int lane = tid & 63;
    const int wv   = tid >> 6;
    const int wm   = (wv >> 1) * 64;
    const int wn   = (wv & 1) * 64;
    const int lrow = lane & 15;
    const int quad = lane >> 4;

    // staging geometry: seg s=0..7 per wave; row = wv*32 + s*4 + (lane>>4)
    // stored chunk slot (lane&15) holds data chunk (lane&15)^(row&7)  [XOR swizzle]
    uint32_t goffA[8];  // byte offset into wb2 tap slab
    uint32_t goffB[8];  // byte offset into xTp (includes b, +1 halo shift), tap-invariant
    #pragma unroll
    for (int s = 0; s < 8; ++s) {
        const int row = wv * 32 + s * 4 + (lane >> 4);
        const int cc  = (lane & 15) ^ (row & 7);
        goffA[s] = (uint32_t)(row * 256 + cc * 16);
        const int l  = l0 + row;
        const int yy = (l >> 6) + 1, xx = (l & 63) + 1;
        const int p  = (b * PW_ + yy) * PW_ + xx;
        goffB[s] = (uint32_t)(p * 256 + cc * 16);
    }

    // pre-pack mask bits: bit (k*4+j) = mask[k][l0+wn+j*16+lrow] != 0
    // 36 bits total -> uint64_t (k*4+j reaches 35; uint32 overflowed in R2)
    uint64_t bits = 0;
    #pragma unroll
    for (int j = 0; j < 4; ++j) {
        const int l = l0 + wn + j * 16 + lrow;
        #pragma unroll
        for (int k = 0; k < 9; ++k)
            if (mask[k * L_ + l] != 0.0f) bits |= (1ull << (k * 4 + j));
    }

    floatx4 acc[4][4];
    #pragma unroll
    for (int i = 0; i < 4; ++i)
        #pragma unroll
        for (int j = 0; j < 4; ++j)
            acc[i][j] = (floatx4){0.f, 0.f, 0.f, 0.f};

    const char* xTp_c = (const char*)xTp;
    const char* wb2_c = (const char*)wb2;
    char* Ab = (char*)A_lds;
    char* Bb = (char*)B_lds;
    const int ldsbase = (wv * 8) * 1024;

    for (int k = 0; k < 9; ++k) {
        const int dy = k / 3 - 1;
        const int dx = k - (k / 3) * 3 - 1;
        const int tapoff = (dy * PW_ + dx) * 256;    // bytes; halo guarantees in-bounds
        const int abase  = k * 32768;                // bytes per tap slab in wb2

        #pragma unroll
        for (int s = 0; s < 8; ++s)
            async_copy16(wb2_c + abase + goffA[s], Ab + ldsbase + s * 1024);
        #pragma unroll
        for (int s = 0; s < 8; ++s)
            async_copy16(xTp_c + (int)goffB[s] + tapoff, Bb + ldsbase + s * 1024);

        __syncthreads();

        uint32_t kp[4];
        #pragma unroll
        for (int j = 0; j < 4; ++j)
            kp[j] = 0u - (uint32_t)((bits >> (k * 4 + j)) & 1ull);

        #pragma unroll
        for (int ks = 0; ks < 4; ++ks) {
            const int sc = ((ks * 4 + quad) ^ (lrow & 7)) * 8;   // swizzled chunk, halves
            bf16x8 af[4], bfr[4];
            #pragma unroll
            for (int i = 0; i < 4; ++i)
                af[i] = *reinterpret_cast<const bf16x8*>(&A_lds[(wm + i * 16 + lrow) * 128 + sc]);
            #pragma unroll
            for (int j = 0; j < 4; ++j) {
                bf16x8 v = *reinterpret_cast<const bf16x8*>(&B_lds[(wn + j * 16 + lrow) * 128 + sc]);
                u32x4 t = __builtin_bit_cast(u32x4, v);
                t &= kp[j];
                bfr[j] = __builtin_bit_cast(bf16x8, t);
            }
            #pragma unroll
            for (int i = 0; i < 4; ++i)
                #pragma unroll
                for (int j = 0; j < 4; ++j)
                    acc[i][j] = __builtin_amdgcn_mfma_f32_16x16x32_bf16(af[i], bfr[j], acc[i][j], 0, 0, 0);
        }
        __syncthreads();
    }

    // epilogue: C/D layout col = lane&15 (l), row = quad*4 + r (o)
    #pragma unroll
    for (int i = 0; i < 4; ++i) {
        #pragma unroll
        for (int j = 0; j < 4; ++j) {
            const int l = l0 + wn + j * 16 + lrow;
            #pragma unroll
            for (int r = 0; r < 4; ++r) {
                const int o = wm + i * 16 + quad * 4 + r;
                out[((size_t)b * COUT_ + o) * L_ + l] = acc[i][j][r] + mb[o * L_ + l];
            }
        }
    }
}

// ---------------------------------------------------------------------------
extern "C" void kernel_launch(void* const* d_in, const int* in_sizes, int n_in,
                              void* d_out, int out_size, void* d_ws, size_t ws_size,
                              hipStream_t stream) {
    const float* x      = (const float*)d_in[0];
    const float* mask   = (const float*)d_in[1];
    const float* weight = (const float*)d_in[2];
    const float* mw     = (const float*)d_in[3];
    const float* bias   = (const float*)d_in[4];
    float* out = (float*)d_out;

    char* ws = (char*)d_ws;
    u16*   xTp = (u16*)ws;                                  // 16*4356*128*2 = 17,842,176 B
    u16*   wb2 = (u16*)(ws + 17842176);                     // 294,912 B  [9][128][128] bf16
    float* mb  = (float*)(ws + 17842176 + 294912);          // 2,097,152 B [128][4096] f32

    lmc_transpose_kernel<<<dim3(64, B_), 256, 0, stream>>>(x, xTp);
    lmc_prep_kernel<<<192, 256, 0, stream>>>(mask, mw, bias, weight, mb, wb2);
    lmc_gemm_kernel<<<dim3(L_ / 128, B_), 256, 0, stream>>>(xTp, wb2, mask, mb, out);
}